// Round 4
// baseline (1008.704 us; speedup 1.0000x reference)
//
#include <hip/hip_runtime.h>

#define NODE_DIM 128
#define EDGE_DIM 64
#define OUT_DIM  128
#define NEG_SLOPE 0.2f

__device__ __forceinline__ float leaky(float v) { return v > 0.f ? v : NEG_SLOPE * v; }

// params buffer layout (floats): [0:128) v_s  [128:256) v_d  [256:320) u_s  [320:384) u_d
//                                [384] c_s  [385] c_d  [386] S3
#define PRM_VS 0
#define PRM_VD 128
#define PRM_US 256
#define PRM_UD 320
#define PRM_CS 384
#define PRM_CD 385
#define PRM_S3 386

// ---------------- K0: zero accumulators ----------------
__global__ __launch_bounds__(256) void k_zero(
    float* __restrict__ Ps, float* __restrict__ Pd, int* __restrict__ cnt,
    float* __restrict__ den, float* __restrict__ wsrc, float* __restrict__ prm, int N)
{
    int i = blockIdx.x * 256 + threadIdx.x;
    if (i < N) { Ps[i] = 0.f; Pd[i] = 0.f; cnt[i] = 0; den[i] = 0.f; wsrc[i] = 0.f; }
    if (i == 0) prm[PRM_S3] = 0.f;
}

// ---------------- K1: tiny precompute of projected vectors ----------------
// v_s = Wg @ att_src (128), u_s = We @ v_s (64), c_s = be . v_s ; same for _d
__global__ void k_prep(const float* __restrict__ We, const float* __restrict__ be,
                       const float* __restrict__ Wg, const float* __restrict__ att_src,
                       const float* __restrict__ att_dst, float* __restrict__ prm)
{
    __shared__ float vs[128], vd[128];
    const int t = threadIdx.x;           // 128 threads
    float s = 0.f, d = 0.f;
    for (int j = 0; j < OUT_DIM; j++) {
        float w = Wg[t * OUT_DIM + j];
        s += w * att_src[j];
        d += w * att_dst[j];
    }
    vs[t] = s; vd[t] = d;
    prm[PRM_VS + t] = s; prm[PRM_VD + t] = d;
    __syncthreads();
    if (t < 64) {
        float us = 0.f, ud = 0.f;
        for (int j = 0; j < NODE_DIM; j++) {
            float w = We[t * NODE_DIM + j];
            us += w * vs[j];
            ud += w * vd[j];
        }
        prm[PRM_US + t] = us; prm[PRM_UD + t] = ud;
    }
    if (t == 0) {
        float cs = 0.f, cd = 0.f;
        for (int j = 0; j < NODE_DIM; j++) { cs += be[j] * vs[j]; cd += be[j] * vd[j]; }
        prm[PRM_CS] = cs; prm[PRM_CD] = cd;
    }
}

// ---------------- K2: stream ea; scatter per-edge scalars P_s,P_d + cnt by dst -------
// 16 lanes per edge, float4 per lane: fully coalesced ea reads
__global__ __launch_bounds__(256) void k_edge1(
    const float* __restrict__ ea, const int* __restrict__ idx, const float* __restrict__ prm,
    float* __restrict__ Ps, float* __restrict__ Pd, int* __restrict__ cnt, int E)
{
    const int q = threadIdx.x & 15;      // quad within edge-group
    const int g = threadIdx.x >> 4;      // 0..15 : edge-group within block
    const float4 u4s = ((const float4*)(prm + PRM_US))[q];
    const float4 u4d = ((const float4*)(prm + PRM_UD))[q];
    for (int e0 = blockIdx.x * 16; e0 < E; e0 += gridDim.x * 16) {
        const int e = e0 + g;
        if (e < E) {
            const int d = idx[E + e];
            const float4 a = ((const float4*)(ea + (size_t)e * EDGE_DIM))[q];
            float ps = a.x * u4s.x + a.y * u4s.y + a.z * u4s.z + a.w * u4s.w;
            float pd = a.x * u4d.x + a.y * u4d.y + a.z * u4d.z + a.w * u4d.w;
            ps += __shfl_xor(ps, 1); pd += __shfl_xor(pd, 1);
            ps += __shfl_xor(ps, 2); pd += __shfl_xor(pd, 2);
            ps += __shfl_xor(ps, 4); pd += __shfl_xor(pd, 4);
            ps += __shfl_xor(ps, 8); pd += __shfl_xor(pd, 8);
            if (q == 0) {
                unsafeAtomicAdd(&Ps[d], ps);
                unsafeAtomicAdd(&Pd[d], pd);
                atomicAdd(&cnt[d], 1);
            }
        }
    }
}

// ---------------- K3: per-node logits a_s,a_d (wave per node) ----------------
__global__ __launch_bounds__(256) void k_nodeA(
    const float* __restrict__ x, const float* __restrict__ prm,
    const float* __restrict__ Ps, const float* __restrict__ Pd, const int* __restrict__ cnt,
    float* __restrict__ a_s, float* __restrict__ a_d, int N)
{
    const int lane = threadIdx.x & 63;
    const float vs0 = prm[PRM_VS + lane], vs1 = prm[PRM_VS + 64 + lane];
    const float vd0 = prm[PRM_VD + lane], vd1 = prm[PRM_VD + 64 + lane];
    const float cs = prm[PRM_CS], cd = prm[PRM_CD];
    const int wid = (blockIdx.x * 256 + threadIdx.x) >> 6;
    const int nw  = (gridDim.x * 256) >> 6;
    for (int n = wid; n < N; n += nw) {
        const float x0 = x[(size_t)n * NODE_DIM + lane];
        const float x1 = x[(size_t)n * NODE_DIM + 64 + lane];
        float gs = x0 * vs0 + x1 * vs1;
        float gd = x0 * vd0 + x1 * vd1;
#pragma unroll
        for (int m = 32; m >= 1; m >>= 1) { gs += __shfl_xor(gs, m); gd += __shfl_xor(gd, m); }
        if (lane == 0) {
            const int c = cnt[n];
            float as_ = gs, ad_ = gd;
            if (c > 0) {
                const float ic = 1.f / (float)c;
                as_ += Ps[n] * ic + cs;
                ad_ += Pd[n] * ic + cd;
            }
            a_s[n] = as_; a_d[n] = ad_;
        }
    }
}

// ---------------- K4: ex[i] = exp(leaky(l)); den[dst] += ex ----------------
__global__ __launch_bounds__(256) void k_den(
    const int* __restrict__ idx, const float* __restrict__ a_s, const float* __restrict__ a_d,
    float* __restrict__ ex, float* __restrict__ den, int E, int N)
{
    const int total = E + N;
    for (int i = blockIdx.x * 256 + threadIdx.x; i < total; i += gridDim.x * 256) {
        int s, d;
        if (i < E) { s = idx[i]; d = idx[E + i]; } else { s = i - E; d = s; }
        float e = __expf(leaky(a_s[s] + a_d[d]));
        ex[i] = e;
        unsafeAtomicAdd(&den[d], e);
    }
}

// ---------------- K5: wsrc[s] += ex[i] / den[d] ----------------
__global__ __launch_bounds__(256) void k_w(
    const int* __restrict__ idx, const float* __restrict__ ex, const float* __restrict__ den,
    float* __restrict__ wsrc, int E, int N)
{
    const int total = E + N;
    for (int i = blockIdx.x * 256 + threadIdx.x; i < total; i += gridDim.x * 256) {
        int s, d;
        if (i < E) { s = idx[i]; d = idx[E + i]; } else { s = i - E; d = s; }
        unsafeAtomicAdd(&wsrc[s], ex[i] / den[d]);
    }
}

// ---------------- K6: accx = sum_n wsrc[n]*x[n] (per-block partials) + S3 ----------------
__global__ __launch_bounds__(256) void k_nodeB(
    const float* __restrict__ x, const float* __restrict__ wsrc, const int* __restrict__ cnt,
    float* __restrict__ partial1, float* __restrict__ prm, int N)
{
    __shared__ float sh[4][128];
    __shared__ float shs[4];
    const int lane = threadIdx.x & 63, w = threadIdx.x >> 6;
    const int wid = (blockIdx.x * 256 + threadIdx.x) >> 6;
    const int nw  = (gridDim.x * 256) >> 6;
    float a0 = 0.f, a1 = 0.f, s3 = 0.f;
    for (int n = wid; n < N; n += 2 * nw) {      // 2 nodes in flight for ILP
        const int n2 = n + nw;
        const float w1 = wsrc[n];
        a0 += w1 * x[(size_t)n * NODE_DIM + lane];
        a1 += w1 * x[(size_t)n * NODE_DIM + 64 + lane];
        if (lane == 0 && cnt[n] > 0) s3 += w1;
        if (n2 < N) {
            const float w2 = wsrc[n2];
            a0 += w2 * x[(size_t)n2 * NODE_DIM + lane];
            a1 += w2 * x[(size_t)n2 * NODE_DIM + 64 + lane];
            if (lane == 0 && cnt[n2] > 0) s3 += w2;
        }
    }
    sh[w][lane] = a0; sh[w][lane + 64] = a1;
    if (lane == 0) shs[w] = s3;
    __syncthreads();
    const int t = threadIdx.x;
    if (t < 128) partial1[(size_t)blockIdx.x * 128 + t] = sh[0][t] + sh[1][t] + sh[2][t] + sh[3][t];
    if (t == 0) unsafeAtomicAdd(&prm[PRM_S3], shs[0] + shs[1] + shs[2] + shs[3]);
}

// ---------------- K7: s64 = sum_e (wsrc/cnt)[dst_e]*ea[e] (per-block partials) ----------
__global__ __launch_bounds__(256) void k_edge2(
    const float* __restrict__ ea, const int* __restrict__ idx,
    const float* __restrict__ wsrc, const int* __restrict__ cnt,
    float* __restrict__ partial2, int E)
{
    const int q = threadIdx.x & 15;
    const int g = threadIdx.x >> 4;
    float4 acc = {0.f, 0.f, 0.f, 0.f};
    for (int e0 = blockIdx.x * 16; e0 < E; e0 += gridDim.x * 16) {
        const int e = e0 + g;
        if (e < E) {
            const int d = idx[E + e];
            const float w = wsrc[d] / (float)max(cnt[d], 1);
            const float4 a = ((const float4*)(ea + (size_t)e * EDGE_DIM))[q];
            acc.x += w * a.x; acc.y += w * a.y; acc.z += w * a.z; acc.w += w * a.w;
        }
    }
    __shared__ float4 sh[16][16];
    sh[g][q] = acc;
    __syncthreads();
    if (threadIdx.x < 16) {
        float4 s = sh[0][threadIdx.x];
        for (int c = 1; c < 16; c++) {
            const float4 v = sh[c][threadIdx.x];
            s.x += v.x; s.y += v.y; s.z += v.z; s.w += v.w;
        }
        ((float4*)(partial2 + (size_t)blockIdx.x * 64))[threadIdx.x] = s;
    }
}

// ---------------- K8: reduce partials; out = (accx + s64@We + S3*be) @ Wg / N + bias ------
__global__ void k_final(const float* __restrict__ partial1, int nb1,
                        const float* __restrict__ partial2, int nb2,
                        const float* __restrict__ prm,
                        const float* __restrict__ We, const float* __restrict__ be,
                        const float* __restrict__ Wg, const float* __restrict__ bias,
                        float* __restrict__ out, float invN)
{
    __shared__ float s64[64], m[128];
    const int t = threadIdx.x;           // 128 threads
    float accx = 0.f;
    for (int b = 0; b < nb1; b++) accx += partial1[(size_t)b * 128 + t];
    if (t < 64) {
        float s = 0.f;
        for (int b = 0; b < nb2; b++) s += partial2[(size_t)b * 64 + t];
        s64[t] = s;
    }
    __syncthreads();
    float t128 = 0.f;
    for (int j = 0; j < EDGE_DIM; j++) t128 += s64[j] * We[j * NODE_DIM + t];
    m[t] = accx + t128 + prm[PRM_S3] * be[t];
    __syncthreads();
    float o = 0.f;
    for (int k = 0; k < NODE_DIM; k++) o += m[k] * Wg[k * OUT_DIM + t];
    out[t] = o * invN + bias[t];
}

extern "C" void kernel_launch(void* const* d_in, const int* in_sizes, int n_in,
                              void* d_out, int out_size, void* d_ws, size_t ws_size,
                              hipStream_t stream)
{
    const float* x       = (const float*)d_in[0];
    const int*   idx     = (const int*)d_in[1];
    const float* ea      = (const float*)d_in[2];
    const float* We      = (const float*)d_in[3];
    const float* be      = (const float*)d_in[4];
    const float* Wg      = (const float*)d_in[5];
    const float* att_src = (const float*)d_in[6];
    const float* att_dst = (const float*)d_in[7];
    const float* bias    = (const float*)d_in[8];
    float* out = (float*)d_out;

    const int N = in_sizes[0] / NODE_DIM;   // 50000
    const int E = in_sizes[1] / 2;          // 800000

    const int NB1 = 1024;   // k_nodeB blocks
    const int NB2 = 2048;   // k_edge2 blocks

    // ws layout (floats), ~6 MB total:
    float* prm      = (float*)d_ws;                       // 512
    float* Ps       = prm + 512;                          // N
    float* Pd       = Ps + N;                             // N
    int*   cnt      = (int*)(Pd + N);                     // N
    float* den      = (float*)(cnt + N);                  // N
    float* a_s      = den + N;                            // N
    float* a_d      = a_s + N;                            // N
    float* wsrc     = a_d + N;                            // N
    float* ex       = wsrc + N;                           // E+N
    float* partial1 = ex + (size_t)E + N;                 // NB1*128
    float* partial2 = partial1 + (size_t)NB1 * 128;       // NB2*64

    k_zero <<<(N + 255) / 256, 256, 0, stream>>>(Ps, Pd, cnt, den, wsrc, prm, N);
    k_prep <<<1, 128, 0, stream>>>(We, be, Wg, att_src, att_dst, prm);
    k_edge1<<<2048, 256, 0, stream>>>(ea, idx, prm, Ps, Pd, cnt, E);
    k_nodeA<<<1024, 256, 0, stream>>>(x, prm, Ps, Pd, cnt, a_s, a_d, N);
    k_den  <<<1024, 256, 0, stream>>>(idx, a_s, a_d, ex, den, E, N);
    k_w    <<<1024, 256, 0, stream>>>(idx, ex, den, wsrc, E, N);
    k_nodeB<<<NB1, 256, 0, stream>>>(x, wsrc, cnt, partial1, prm, N);
    k_edge2<<<NB2, 256, 0, stream>>>(ea, idx, wsrc, cnt, partial2, E);
    k_final<<<1, 128, 0, stream>>>(partial1, NB1, partial2, NB2, prm, We, be, Wg, bias, out, 1.0f / N);
}

// Round 5
// 516.172 us; speedup vs baseline: 1.9542x; 1.9542x over previous
//
#include <hip/hip_runtime.h>

#define NODE_DIM 128
#define EDGE_DIM 64
#define OUT_DIM  128
#define NEG_SLOPE 0.2f

__device__ __forceinline__ float leaky(float v) { return v > 0.f ? v : NEG_SLOPE * v; }

// params/accumulator buffer layout (floats):
// [0:128) v_s  [128:256) v_d  [256:320) u_s  [320:384) u_d  [384] c_s  [385] c_d  [386] S3
// [512:640) accx  [640:704) s64
#define PRM_VS   0
#define PRM_VD   128
#define PRM_US   256
#define PRM_UD   320
#define PRM_CS   384
#define PRM_CD   385
#define PRM_S3   386
#define PRM_ACCX 512
#define PRM_S64  640

// ---------------- K0: zero accumulators ----------------
__global__ __launch_bounds__(256) void k_zero(
    float* __restrict__ Ps, float* __restrict__ Pd, int* __restrict__ cnt,
    float* __restrict__ den, float* __restrict__ wsrc, float* __restrict__ prm, int N)
{
    int i = blockIdx.x * 256 + threadIdx.x;
    if (i < N) { Ps[i] = 0.f; Pd[i] = 0.f; cnt[i] = 0; den[i] = 0.f; wsrc[i] = 0.f; }
    if (i < 128) prm[PRM_ACCX + i] = 0.f;
    if (i < 64)  prm[PRM_S64 + i] = 0.f;
    if (i == 0)  prm[PRM_S3] = 0.f;
}

// ---------------- K1: projected vectors (wave-parallel, coalesced) ----------------
// v_s = Wg @ att_src (128), u_s = We @ v_s (64), c_s = be . v_s ; same for _d
__global__ __launch_bounds__(256) void k_prep(
    const float* __restrict__ We, const float* __restrict__ be,
    const float* __restrict__ Wg, const float* __restrict__ att_src,
    const float* __restrict__ att_dst, float* __restrict__ prm)
{
    __shared__ float vs[128], vd[128];
    const int lane = threadIdx.x & 63, w = threadIdx.x >> 6;  // 4 waves
    const float as0 = att_src[lane], as1 = att_src[64 + lane];
    const float ad0 = att_dst[lane], ad1 = att_dst[64 + lane];
    for (int r = w; r < NODE_DIM; r += 4) {
        const float w0 = Wg[r * OUT_DIM + lane], w1 = Wg[r * OUT_DIM + 64 + lane];
        float s = w0 * as0 + w1 * as1;
        float d = w0 * ad0 + w1 * ad1;
#pragma unroll
        for (int m = 32; m >= 1; m >>= 1) { s += __shfl_xor(s, m); d += __shfl_xor(d, m); }
        if (lane == 0) { vs[r] = s; vd[r] = d; prm[PRM_VS + r] = s; prm[PRM_VD + r] = d; }
    }
    __syncthreads();
    const float bv0 = vs[lane], bv1 = vs[64 + lane];
    const float bw0 = vd[lane], bw1 = vd[64 + lane];
    for (int r = w; r < EDGE_DIM; r += 4) {
        const float w0 = We[r * NODE_DIM + lane], w1 = We[r * NODE_DIM + 64 + lane];
        float us = w0 * bv0 + w1 * bv1;
        float ud = w0 * bw0 + w1 * bw1;
#pragma unroll
        for (int m = 32; m >= 1; m >>= 1) { us += __shfl_xor(us, m); ud += __shfl_xor(ud, m); }
        if (lane == 0) { prm[PRM_US + r] = us; prm[PRM_UD + r] = ud; }
    }
    if (w == 0) {
        const float b0 = be[lane], b1 = be[64 + lane];
        float cs = b0 * bv0 + b1 * bv1;
        float cd = b0 * bw0 + b1 * bw1;
#pragma unroll
        for (int m = 32; m >= 1; m >>= 1) { cs += __shfl_xor(cs, m); cd += __shfl_xor(cd, m); }
        if (lane == 0) { prm[PRM_CS] = cs; prm[PRM_CD] = cd; }
    }
}

// ---------------- K2: stream ea; scatter per-edge scalars P_s,P_d + cnt by dst -------
__global__ __launch_bounds__(256) void k_edge1(
    const float* __restrict__ ea, const int* __restrict__ idx, const float* __restrict__ prm,
    float* __restrict__ Ps, float* __restrict__ Pd, int* __restrict__ cnt, int E)
{
    const int q = threadIdx.x & 15;      // quad within edge
    const int g = threadIdx.x >> 4;      // edge-group within block
    const float4 u4s = ((const float4*)(prm + PRM_US))[q];
    const float4 u4d = ((const float4*)(prm + PRM_UD))[q];
    for (int e0 = blockIdx.x * 16; e0 < E; e0 += gridDim.x * 16) {
        const int e = e0 + g;
        if (e < E) {
            const int d = idx[E + e];
            const float4 a = ((const float4*)(ea + (size_t)e * EDGE_DIM))[q];
            float ps = a.x * u4s.x + a.y * u4s.y + a.z * u4s.z + a.w * u4s.w;
            float pd = a.x * u4d.x + a.y * u4d.y + a.z * u4d.z + a.w * u4d.w;
            ps += __shfl_xor(ps, 1); pd += __shfl_xor(pd, 1);
            ps += __shfl_xor(ps, 2); pd += __shfl_xor(pd, 2);
            ps += __shfl_xor(ps, 4); pd += __shfl_xor(pd, 4);
            ps += __shfl_xor(ps, 8); pd += __shfl_xor(pd, 8);
            if (q == 0) {
                unsafeAtomicAdd(&Ps[d], ps);
                unsafeAtomicAdd(&Pd[d], pd);
                atomicAdd(&cnt[d], 1);
            }
        }
    }
}

// ---------------- K3: per-node logits a_s,a_d (wave per node) ----------------
__global__ __launch_bounds__(256) void k_nodeA(
    const float* __restrict__ x, const float* __restrict__ prm,
    const float* __restrict__ Ps, const float* __restrict__ Pd, const int* __restrict__ cnt,
    float* __restrict__ a_s, float* __restrict__ a_d, int N)
{
    const int lane = threadIdx.x & 63;
    const float vs0 = prm[PRM_VS + lane], vs1 = prm[PRM_VS + 64 + lane];
    const float vd0 = prm[PRM_VD + lane], vd1 = prm[PRM_VD + 64 + lane];
    const float cs = prm[PRM_CS], cd = prm[PRM_CD];
    const int wid = (blockIdx.x * 256 + threadIdx.x) >> 6;
    const int nw  = (gridDim.x * 256) >> 6;
    for (int n = wid; n < N; n += nw) {
        const float x0 = x[(size_t)n * NODE_DIM + lane];
        const float x1 = x[(size_t)n * NODE_DIM + 64 + lane];
        float gs = x0 * vs0 + x1 * vs1;
        float gd = x0 * vd0 + x1 * vd1;
#pragma unroll
        for (int m = 32; m >= 1; m >>= 1) { gs += __shfl_xor(gs, m); gd += __shfl_xor(gd, m); }
        if (lane == 0) {
            const int c = cnt[n];
            float as_ = gs, ad_ = gd;
            if (c > 0) {
                const float ic = 1.f / (float)c;
                as_ += Ps[n] * ic + cs;
                ad_ += Pd[n] * ic + cd;
            }
            a_s[n] = as_; a_d[n] = ad_;
        }
    }
}

// ---------------- K4: ex[i] = exp(leaky(l)); den[dst] += ex ----------------
__global__ __launch_bounds__(256) void k_den(
    const int* __restrict__ idx, const float* __restrict__ a_s, const float* __restrict__ a_d,
    float* __restrict__ ex, float* __restrict__ den, int E, int N)
{
    const int total = E + N;
    for (int i = blockIdx.x * 256 + threadIdx.x; i < total; i += gridDim.x * 256) {
        int s, d;
        if (i < E) { s = idx[i]; d = idx[E + i]; } else { s = i - E; d = s; }
        float e = __expf(leaky(a_s[s] + a_d[d]));
        ex[i] = e;
        unsafeAtomicAdd(&den[d], e);
    }
}

// ---------------- K5: wsrc[s] += ex[i] / den[d] ----------------
__global__ __launch_bounds__(256) void k_w(
    const int* __restrict__ idx, const float* __restrict__ ex, const float* __restrict__ den,
    float* __restrict__ wsrc, int E, int N)
{
    const int total = E + N;
    for (int i = blockIdx.x * 256 + threadIdx.x; i < total; i += gridDim.x * 256) {
        int s, d;
        if (i < E) { s = idx[i]; d = idx[E + i]; } else { s = i - E; d = s; }
        unsafeAtomicAdd(&wsrc[s], ex[i] / den[d]);
    }
}

// ---------------- K6: accx += sum_n wsrc[n]*x[n]; S3 += sum wsrc (atomic into prm) -------
__global__ __launch_bounds__(256) void k_nodeB(
    const float* __restrict__ x, const float* __restrict__ wsrc, const int* __restrict__ cnt,
    float* __restrict__ prm, int N)
{
    __shared__ float sh[4][128];
    __shared__ float shs[4];
    const int lane = threadIdx.x & 63, w = threadIdx.x >> 6;
    const int wid = (blockIdx.x * 256 + threadIdx.x) >> 6;
    const int nw  = (gridDim.x * 256) >> 6;
    float a0 = 0.f, a1 = 0.f, s3 = 0.f;
    for (int n = wid; n < N; n += 2 * nw) {
        const int n2 = n + nw;
        const float w1 = wsrc[n];
        a0 += w1 * x[(size_t)n * NODE_DIM + lane];
        a1 += w1 * x[(size_t)n * NODE_DIM + 64 + lane];
        if (lane == 0 && cnt[n] > 0) s3 += w1;
        if (n2 < N) {
            const float w2 = wsrc[n2];
            a0 += w2 * x[(size_t)n2 * NODE_DIM + lane];
            a1 += w2 * x[(size_t)n2 * NODE_DIM + 64 + lane];
            if (lane == 0 && cnt[n2] > 0) s3 += w2;
        }
    }
    sh[w][lane] = a0; sh[w][lane + 64] = a1;
    if (lane == 0) shs[w] = s3;
    __syncthreads();
    const int t = threadIdx.x;
    if (t < 128)
        unsafeAtomicAdd(&prm[PRM_ACCX + t], sh[0][t] + sh[1][t] + sh[2][t] + sh[3][t]);
    if (t == 0)
        unsafeAtomicAdd(&prm[PRM_S3], shs[0] + shs[1] + shs[2] + shs[3]);
}

// ---------------- K7: s64 += sum_e (wsrc/cnt)[dst_e]*ea[e] (atomic into prm) ----------
__global__ __launch_bounds__(256) void k_edge2(
    const float* __restrict__ ea, const int* __restrict__ idx,
    const float* __restrict__ wsrc, const int* __restrict__ cnt,
    float* __restrict__ prm, int E)
{
    const int q = threadIdx.x & 15;
    const int g = threadIdx.x >> 4;
    float4 acc = {0.f, 0.f, 0.f, 0.f};
    for (int e0 = blockIdx.x * 16; e0 < E; e0 += gridDim.x * 16) {
        const int e = e0 + g;
        if (e < E) {
            const int d = idx[E + e];
            const float w = wsrc[d] / (float)max(cnt[d], 1);
            const float4 a = ((const float4*)(ea + (size_t)e * EDGE_DIM))[q];
            acc.x += w * a.x; acc.y += w * a.y; acc.z += w * a.z; acc.w += w * a.w;
        }
    }
    __shared__ float4 sh[16][16];
    sh[g][q] = acc;
    __syncthreads();
    if (threadIdx.x < 16) {
        float4 s = sh[0][threadIdx.x];
        for (int c = 1; c < 16; c++) {
            const float4 v = sh[c][threadIdx.x];
            s.x += v.x; s.y += v.y; s.z += v.z; s.w += v.w;
        }
        float* dst = prm + PRM_S64 + threadIdx.x * 4;
        unsafeAtomicAdd(dst + 0, s.x);
        unsafeAtomicAdd(dst + 1, s.y);
        unsafeAtomicAdd(dst + 2, s.z);
        unsafeAtomicAdd(dst + 3, s.w);
    }
}

// ---------------- K8: out = (accx + s64@We + S3*be) @ Wg / N + bias ------
__global__ void k_final(const float* __restrict__ prm,
                        const float* __restrict__ We, const float* __restrict__ be,
                        const float* __restrict__ Wg, const float* __restrict__ bias,
                        float* __restrict__ out, float invN)
{
    __shared__ float s64[64], m[128];
    const int t = threadIdx.x;           // 128 threads
    if (t < 64) s64[t] = prm[PRM_S64 + t];
    __syncthreads();
    float t128 = 0.f;
    for (int j = 0; j < EDGE_DIM; j++) t128 += s64[j] * We[j * NODE_DIM + t];
    m[t] = prm[PRM_ACCX + t] + t128 + prm[PRM_S3] * be[t];
    __syncthreads();
    float o = 0.f;
    for (int k = 0; k < NODE_DIM; k++) o += m[k] * Wg[k * OUT_DIM + t];
    out[t] = o * invN + bias[t];
}

extern "C" void kernel_launch(void* const* d_in, const int* in_sizes, int n_in,
                              void* d_out, int out_size, void* d_ws, size_t ws_size,
                              hipStream_t stream)
{
    const float* x       = (const float*)d_in[0];
    const int*   idx     = (const int*)d_in[1];
    const float* ea      = (const float*)d_in[2];
    const float* We      = (const float*)d_in[3];
    const float* be      = (const float*)d_in[4];
    const float* Wg      = (const float*)d_in[5];
    const float* att_src = (const float*)d_in[6];
    const float* att_dst = (const float*)d_in[7];
    const float* bias    = (const float*)d_in[8];
    float* out = (float*)d_out;

    const int N = in_sizes[0] / NODE_DIM;   // 50000
    const int E = in_sizes[1] / 2;          // 800000

    // ws layout (floats), ~5 MB total:
    float* prm  = (float*)d_ws;                 // 1024
    float* Ps   = prm + 1024;                   // N
    float* Pd   = Ps + N;                       // N
    int*   cnt  = (int*)(Pd + N);               // N
    float* den  = (float*)(cnt + N);            // N
    float* a_s  = den + N;                      // N
    float* a_d  = a_s + N;                      // N
    float* wsrc = a_d + N;                      // N
    float* ex   = wsrc + N;                     // E+N

    k_zero <<<(N + 255) / 256, 256, 0, stream>>>(Ps, Pd, cnt, den, wsrc, prm, N);
    k_prep <<<1, 256, 0, stream>>>(We, be, Wg, att_src, att_dst, prm);
    k_edge1<<<2048, 256, 0, stream>>>(ea, idx, prm, Ps, Pd, cnt, E);
    k_nodeA<<<1024, 256, 0, stream>>>(x, prm, Ps, Pd, cnt, a_s, a_d, N);
    k_den  <<<1024, 256, 0, stream>>>(idx, a_s, a_d, ex, den, E, N);
    k_w    <<<1024, 256, 0, stream>>>(idx, ex, den, wsrc, E, N);
    k_nodeB<<<1024, 256, 0, stream>>>(x, wsrc, cnt, prm, N);
    k_edge2<<<2048, 256, 0, stream>>>(ea, idx, wsrc, cnt, prm, E);
    k_final<<<1, 128, 0, stream>>>(prm, We, be, Wg, bias, out, 1.0f / N);
}

// Round 6
// 324.416 us; speedup vs baseline: 3.1093x; 1.5911x over previous
//
#include <hip/hip_runtime.h>

#define NODE_DIM 128
#define EDGE_DIM 64
#define OUT_DIM  128
#define NEG_SLOPE 0.2f
#define NREP 16

__device__ __forceinline__ float leaky(float v) { return v > 0.f ? v : NEG_SLOPE * v; }

// params/accumulator buffer layout (floats), 4096 total:
// [0:128) v_s  [128:256) v_d  [256:320) u_s  [320:384) u_d  [384] c_s  [385] c_d  [386] S3
// [512:2560) accx replicas (16 x 128)   [2560:3584) s64 replicas (16 x 64)
#define PRM_VS    0
#define PRM_VD    128
#define PRM_US    256
#define PRM_UD    320
#define PRM_CS    384
#define PRM_CD    385
#define PRM_S3    386
#define PRM_ACCXR 512
#define PRM_S64R  2560
#define PRM_SIZE  4096

// ---------------- K0: zero accumulators ----------------
__global__ __launch_bounds__(256) void k_zero(
    float* __restrict__ Ps, float* __restrict__ Pd, int* __restrict__ cnt,
    float* __restrict__ den, float* __restrict__ wsrc, float* __restrict__ prm, int N)
{
    int i = blockIdx.x * 256 + threadIdx.x;
    if (i < N) { Ps[i] = 0.f; Pd[i] = 0.f; cnt[i] = 0; den[i] = 0.f; wsrc[i] = 0.f; }
    if (i < PRM_SIZE) prm[i] = 0.f;
}

// ---------------- K1: projected vectors (wave-parallel, coalesced) ----------------
// v_s = Wg @ att_src (128), u_s = We @ v_s (64), c_s = be . v_s ; same for _d
__global__ __launch_bounds__(256) void k_prep(
    const float* __restrict__ We, const float* __restrict__ be,
    const float* __restrict__ Wg, const float* __restrict__ att_src,
    const float* __restrict__ att_dst, float* __restrict__ prm)
{
    __shared__ float vs[128], vd[128];
    const int lane = threadIdx.x & 63, w = threadIdx.x >> 6;  // 4 waves
    const float as0 = att_src[lane], as1 = att_src[64 + lane];
    const float ad0 = att_dst[lane], ad1 = att_dst[64 + lane];
    for (int r = w; r < NODE_DIM; r += 4) {
        const float w0 = Wg[r * OUT_DIM + lane], w1 = Wg[r * OUT_DIM + 64 + lane];
        float s = w0 * as0 + w1 * as1;
        float d = w0 * ad0 + w1 * ad1;
#pragma unroll
        for (int m = 32; m >= 1; m >>= 1) { s += __shfl_xor(s, m); d += __shfl_xor(d, m); }
        if (lane == 0) { vs[r] = s; vd[r] = d; prm[PRM_VS + r] = s; prm[PRM_VD + r] = d; }
    }
    __syncthreads();
    const float bv0 = vs[lane], bv1 = vs[64 + lane];
    const float bw0 = vd[lane], bw1 = vd[64 + lane];
    for (int r = w; r < EDGE_DIM; r += 4) {
        const float w0 = We[r * NODE_DIM + lane], w1 = We[r * NODE_DIM + 64 + lane];
        float us = w0 * bv0 + w1 * bv1;
        float ud = w0 * bw0 + w1 * bw1;
#pragma unroll
        for (int m = 32; m >= 1; m >>= 1) { us += __shfl_xor(us, m); ud += __shfl_xor(ud, m); }
        if (lane == 0) { prm[PRM_US + r] = us; prm[PRM_UD + r] = ud; }
    }
    if (w == 0) {
        const float b0 = be[lane], b1 = be[64 + lane];
        float cs = b0 * bv0 + b1 * bv1;
        float cd = b0 * bw0 + b1 * bw1;
#pragma unroll
        for (int m = 32; m >= 1; m >>= 1) { cs += __shfl_xor(cs, m); cd += __shfl_xor(cd, m); }
        if (lane == 0) { prm[PRM_CS] = cs; prm[PRM_CD] = cd; }
    }
}

// ---------------- K2: stream ea; scatter per-edge scalars P_s,P_d + cnt by dst -------
__global__ __launch_bounds__(256) void k_edge1(
    const float* __restrict__ ea, const int* __restrict__ idx, const float* __restrict__ prm,
    float* __restrict__ Ps, float* __restrict__ Pd, int* __restrict__ cnt, int E)
{
    const int q = threadIdx.x & 15;      // quad within edge
    const int g = threadIdx.x >> 4;      // edge-group within block
    const float4 u4s = ((const float4*)(prm + PRM_US))[q];
    const float4 u4d = ((const float4*)(prm + PRM_UD))[q];
    for (int e0 = blockIdx.x * 16; e0 < E; e0 += gridDim.x * 16) {
        const int e = e0 + g;
        if (e < E) {
            const int d = idx[E + e];
            const float4 a = ((const float4*)(ea + (size_t)e * EDGE_DIM))[q];
            float ps = a.x * u4s.x + a.y * u4s.y + a.z * u4s.z + a.w * u4s.w;
            float pd = a.x * u4d.x + a.y * u4d.y + a.z * u4d.z + a.w * u4d.w;
            ps += __shfl_xor(ps, 1); pd += __shfl_xor(pd, 1);
            ps += __shfl_xor(ps, 2); pd += __shfl_xor(pd, 2);
            ps += __shfl_xor(ps, 4); pd += __shfl_xor(pd, 4);
            ps += __shfl_xor(ps, 8); pd += __shfl_xor(pd, 8);
            if (q == 0) {
                unsafeAtomicAdd(&Ps[d], ps);
                unsafeAtomicAdd(&Pd[d], pd);
                atomicAdd(&cnt[d], 1);
            }
        }
    }
}

// ---------------- K3: per-node logits a_s,a_d (wave per node) ----------------
__global__ __launch_bounds__(256) void k_nodeA(
    const float* __restrict__ x, const float* __restrict__ prm,
    const float* __restrict__ Ps, const float* __restrict__ Pd, const int* __restrict__ cnt,
    float* __restrict__ a_s, float* __restrict__ a_d, int N)
{
    const int lane = threadIdx.x & 63;
    const float vs0 = prm[PRM_VS + lane], vs1 = prm[PRM_VS + 64 + lane];
    const float vd0 = prm[PRM_VD + lane], vd1 = prm[PRM_VD + 64 + lane];
    const float cs = prm[PRM_CS], cd = prm[PRM_CD];
    const int wid = (blockIdx.x * 256 + threadIdx.x) >> 6;
    const int nw  = (gridDim.x * 256) >> 6;
    for (int n = wid; n < N; n += nw) {
        const float x0 = x[(size_t)n * NODE_DIM + lane];
        const float x1 = x[(size_t)n * NODE_DIM + 64 + lane];
        float gs = x0 * vs0 + x1 * vs1;
        float gd = x0 * vd0 + x1 * vd1;
#pragma unroll
        for (int m = 32; m >= 1; m >>= 1) { gs += __shfl_xor(gs, m); gd += __shfl_xor(gd, m); }
        if (lane == 0) {
            const int c = cnt[n];
            float as_ = gs, ad_ = gd;
            if (c > 0) {
                const float ic = 1.f / (float)c;
                as_ += Ps[n] * ic + cs;
                ad_ += Pd[n] * ic + cd;
            }
            a_s[n] = as_; a_d[n] = ad_;
        }
    }
}

// ---------------- K4: ex[i] = exp(leaky(l)); den[dst] += ex ----------------
__global__ __launch_bounds__(256) void k_den(
    const int* __restrict__ idx, const float* __restrict__ a_s, const float* __restrict__ a_d,
    float* __restrict__ ex, float* __restrict__ den, int E, int N)
{
    const int total = E + N;
    for (int i = blockIdx.x * 256 + threadIdx.x; i < total; i += gridDim.x * 256) {
        int s, d;
        if (i < E) { s = idx[i]; d = idx[E + i]; } else { s = i - E; d = s; }
        float e = __expf(leaky(a_s[s] + a_d[d]));
        ex[i] = e;
        unsafeAtomicAdd(&den[d], e);
    }
}

// ---------------- K5: wsrc[s] += ex[i] / den[d] ----------------
__global__ __launch_bounds__(256) void k_w(
    const int* __restrict__ idx, const float* __restrict__ ex, const float* __restrict__ den,
    float* __restrict__ wsrc, int E, int N)
{
    const int total = E + N;
    for (int i = blockIdx.x * 256 + threadIdx.x; i < total; i += gridDim.x * 256) {
        int s, d;
        if (i < E) { s = idx[i]; d = idx[E + i]; } else { s = i - E; d = s; }
        unsafeAtomicAdd(&wsrc[s], ex[i] / den[d]);
    }
}

// ---------------- K5b: wnorm[n] = wsrc[n]/max(cnt,1); S3 += sum_{cnt>0} wsrc ----------
__global__ __launch_bounds__(256) void k_wnorm(
    const float* __restrict__ wsrc, const int* __restrict__ cnt,
    float* __restrict__ wnorm, float* __restrict__ prm, int N)
{
    const int i = blockIdx.x * 256 + threadIdx.x;
    float s3 = 0.f;
    if (i < N) {
        const float ws = wsrc[i];
        const int c = cnt[i];
        wnorm[i] = ws / (float)max(c, 1);
        if (c > 0) s3 = ws;
    }
#pragma unroll
    for (int m = 32; m >= 1; m >>= 1) s3 += __shfl_xor(s3, m);
    if ((threadIdx.x & 63) == 0) unsafeAtomicAdd(&prm[PRM_S3], s3);
}

// ---------------- K5c: wedge[e] = wnorm[dst_e] (independent gathers, TLP-hidden) ------
__global__ __launch_bounds__(256) void k_edgeW(
    const int* __restrict__ idx, const float* __restrict__ wnorm,
    float* __restrict__ wedge, int E)
{
    for (int e = blockIdx.x * 256 + threadIdx.x; e < E; e += gridDim.x * 256)
        wedge[e] = wnorm[idx[E + e]];
}

// ---------------- K6: accx += sum_n wsrc[n]*x[n] (replicated atomic slots) ----------
__global__ __launch_bounds__(256) void k_nodeB(
    const float* __restrict__ x, const float* __restrict__ wsrc,
    float* __restrict__ prm, int N)
{
    __shared__ float sh[4][128];
    const int lane = threadIdx.x & 63, w = threadIdx.x >> 6;
    const int wid = (blockIdx.x * 256 + threadIdx.x) >> 6;
    const int nw  = (gridDim.x * 256) >> 6;
    float a0 = 0.f, a1 = 0.f;
    for (int n = wid; n < N; n += 2 * nw) {
        const int n2 = n + nw;
        const float w1 = wsrc[n];
        a0 += w1 * x[(size_t)n * NODE_DIM + lane];
        a1 += w1 * x[(size_t)n * NODE_DIM + 64 + lane];
        if (n2 < N) {
            const float w2 = wsrc[n2];
            a0 += w2 * x[(size_t)n2 * NODE_DIM + lane];
            a1 += w2 * x[(size_t)n2 * NODE_DIM + 64 + lane];
        }
    }
    sh[w][lane] = a0; sh[w][lane + 64] = a1;
    __syncthreads();
    const int t = threadIdx.x;
    if (t < 128) {
        float* dst = prm + PRM_ACCXR + (blockIdx.x & (NREP - 1)) * 128;
        unsafeAtomicAdd(&dst[t], sh[0][t] + sh[1][t] + sh[2][t] + sh[3][t]);
    }
}

// ---------------- K7: s64 += sum_e wedge[e]*ea[e] (pure affine stream) ----------
__global__ __launch_bounds__(256) void k_edge2(
    const float* __restrict__ ea, const float* __restrict__ wedge,
    float* __restrict__ prm, int E)
{
    const int q = threadIdx.x & 15;
    const int g = threadIdx.x >> 4;
    float4 acc = {0.f, 0.f, 0.f, 0.f};
    for (int e0 = blockIdx.x * 16; e0 < E; e0 += gridDim.x * 16) {
        const int e = e0 + g;
        if (e < E) {
            const float w = wedge[e];
            const float4 a = ((const float4*)(ea + (size_t)e * EDGE_DIM))[q];
            acc.x += w * a.x; acc.y += w * a.y; acc.z += w * a.z; acc.w += w * a.w;
        }
    }
    __shared__ float4 sh[16][16];
    sh[g][q] = acc;
    __syncthreads();
    if (threadIdx.x < 16) {
        float4 s = sh[0][threadIdx.x];
        for (int c = 1; c < 16; c++) {
            const float4 v = sh[c][threadIdx.x];
            s.x += v.x; s.y += v.y; s.z += v.z; s.w += v.w;
        }
        float* dst = prm + PRM_S64R + (blockIdx.x & (NREP - 1)) * 64 + threadIdx.x * 4;
        unsafeAtomicAdd(dst + 0, s.x);
        unsafeAtomicAdd(dst + 1, s.y);
        unsafeAtomicAdd(dst + 2, s.z);
        unsafeAtomicAdd(dst + 3, s.w);
    }
}

// ---------------- K8: out = (accx + s64@We + S3*be) @ Wg / N + bias ------
__global__ void k_final(const float* __restrict__ prm,
                        const float* __restrict__ We, const float* __restrict__ be,
                        const float* __restrict__ Wg, const float* __restrict__ bias,
                        float* __restrict__ out, float invN)
{
    __shared__ float s64[64], m[128];
    const int t = threadIdx.x;           // 128 threads
    if (t < 64) {
        float s = 0.f;
        for (int r = 0; r < NREP; r++) s += prm[PRM_S64R + r * 64 + t];
        s64[t] = s;
    }
    float accx = 0.f;
    for (int r = 0; r < NREP; r++) accx += prm[PRM_ACCXR + r * 128 + t];
    __syncthreads();
    float t128 = 0.f;
    for (int j = 0; j < EDGE_DIM; j++) t128 += s64[j] * We[j * NODE_DIM + t];
    m[t] = accx + t128 + prm[PRM_S3] * be[t];
    __syncthreads();
    float o = 0.f;
    for (int k = 0; k < NODE_DIM; k++) o += m[k] * Wg[k * OUT_DIM + t];
    out[t] = o * invN + bias[t];
}

extern "C" void kernel_launch(void* const* d_in, const int* in_sizes, int n_in,
                              void* d_out, int out_size, void* d_ws, size_t ws_size,
                              hipStream_t stream)
{
    const float* x       = (const float*)d_in[0];
    const int*   idx     = (const int*)d_in[1];
    const float* ea      = (const float*)d_in[2];
    const float* We      = (const float*)d_in[3];
    const float* be      = (const float*)d_in[4];
    const float* Wg      = (const float*)d_in[5];
    const float* att_src = (const float*)d_in[6];
    const float* att_dst = (const float*)d_in[7];
    const float* bias    = (const float*)d_in[8];
    float* out = (float*)d_out;

    const int N = in_sizes[0] / NODE_DIM;   // 50000
    const int E = in_sizes[1] / 2;          // 800000

    // ws layout (floats), ~10 MB total:
    float* prm   = (float*)d_ws;                 // PRM_SIZE
    float* Ps    = prm + PRM_SIZE;               // N
    float* Pd    = Ps + N;                       // N
    int*   cnt   = (int*)(Pd + N);               // N
    float* den   = (float*)(cnt + N);            // N
    float* a_s   = den + N;                      // N
    float* a_d   = a_s + N;                      // N
    float* wsrc  = a_d + N;                      // N
    float* wnorm = wsrc + N;                     // N
    float* ex    = wnorm + N;                    // E+N
    float* wedge = ex + (size_t)E + N;           // E

    k_zero <<<(N + 255) / 256, 256, 0, stream>>>(Ps, Pd, cnt, den, wsrc, prm, N);
    k_prep <<<1, 256, 0, stream>>>(We, be, Wg, att_src, att_dst, prm);
    k_edge1<<<2048, 256, 0, stream>>>(ea, idx, prm, Ps, Pd, cnt, E);
    k_nodeA<<<1024, 256, 0, stream>>>(x, prm, Ps, Pd, cnt, a_s, a_d, N);
    k_den  <<<1024, 256, 0, stream>>>(idx, a_s, a_d, ex, den, E, N);
    k_w    <<<1024, 256, 0, stream>>>(idx, ex, den, wsrc, E, N);
    k_wnorm<<<(N + 255) / 256, 256, 0, stream>>>(wsrc, cnt, wnorm, prm, N);
    k_edgeW<<<1024, 256, 0, stream>>>(idx, wnorm, wedge, E);
    k_nodeB<<<512, 256, 0, stream>>>(x, wsrc, prm, N);
    k_edge2<<<1024, 256, 0, stream>>>(ea, wedge, prm, E);
    k_final<<<1, 128, 0, stream>>>(prm, We, be, Wg, bias, out, 1.0f / N);
}